// Round 1
// baseline (528.103 us; speedup 1.0000x reference)
//
#include <hip/hip_runtime.h>
#include <math.h>

#define NS 100000
#define NC 64
#define ND 32

// ws layout (floats):
//   A      [NC*ND*ND]  = L^{-1} per component (row-major, upper part zero)
//   c      [NC*ND]     = A_k * mu_k
//   kconst [NC]        = -0.5*D*log(2pi) - sum(log diag L_k)
//   lw     [NC]        = log_softmax(log_weights)
//   acc    [1]         = sum of per-sample log-likelihoods

__global__ void gmm_setup(const float* __restrict__ means,
                          const float* __restrict__ scale_tril,
                          const float* __restrict__ log_weights,
                          float* __restrict__ A,
                          float* __restrict__ c,
                          float* __restrict__ kconst,
                          float* __restrict__ lw,
                          float* __restrict__ acc) {
    int k = blockIdx.x;      // component
    int j = threadIdx.x;     // column of A (0..31)
    const float* L = scale_tril + (size_t)k * ND * ND;
    __shared__ float Acol[ND][ND + 1];

    // Forward substitution: column j of A = L^{-1}. Each thread owns its column.
    for (int i = 0; i < ND; ++i) {
        float s = (i == j) ? 1.0f : 0.0f;
        for (int l = j; l < i; ++l) s -= L[i * ND + l] * Acol[l][j];
        Acol[i][j] = (i >= j) ? (s / L[i * ND + i]) : 0.0f;
    }

    float* Ak = A + (size_t)k * ND * ND;
    for (int i = 0; i < ND; ++i) Ak[i * ND + j] = Acol[i][j];
    __syncthreads();

    // c[i] = sum_t A[i][t] * mu[t]; reuse thread index as row index
    const float* mu = means + k * ND;
    float cv = 0.0f;
    for (int t = 0; t < ND; ++t) cv += Acol[j][t] * mu[t];
    c[k * ND + j] = cv;

    if (j == 0) {
        float hld = 0.0f;
        for (int i = 0; i < ND; ++i) hld += logf(L[i * ND + i]);
        const float LOG2PI = 1.8378770664093453f;
        kconst[k] = -0.5f * (float)ND * LOG2PI - hld;
        // log_softmax over the 64 log-weights (redundant per block; trivial)
        float mx = log_weights[0];
        for (int t = 1; t < NC; ++t) mx = fmaxf(mx, log_weights[t]);
        float se = 0.0f;
        for (int t = 0; t < NC; ++t) se += __expf(log_weights[t] - mx);
        lw[k] = log_weights[k] - mx - logf(se);
        if (k == 0) acc[0] = 0.0f;   // ws is re-poisoned before every launch
    }
}

__launch_bounds__(64)
__global__ void gmm_main(const float* __restrict__ X,
                         const float* __restrict__ A,
                         const float* __restrict__ c,
                         const float* __restrict__ kconst,
                         const float* __restrict__ lw,
                         float* __restrict__ acc) {
    int n = blockIdx.x * 64 + threadIdx.x;
    bool active = (n < NS);
    int nn = active ? n : 0;

    float x[ND];
    const float4* Xv = (const float4*)(X + (size_t)nn * ND);
#pragma unroll
    for (int q = 0; q < ND / 4; ++q) {
        float4 v = Xv[q];
        x[4 * q + 0] = v.x; x[4 * q + 1] = v.y;
        x[4 * q + 2] = v.z; x[4 * q + 3] = v.w;
    }

    // online softmax state over components
    float m = -1e30f, s = 0.0f, w = 0.0f;

    for (int k = 0; k < NC; ++k) {
        const float* Ak = A + k * (ND * ND);   // wave-uniform address -> s_load
        const float* ck = c + k * ND;
        float maha = 0.0f;
#pragma unroll
        for (int i = 0; i < ND; ++i) {
            float z = -ck[i];
#pragma unroll
            for (int j = 0; j <= i; ++j) z = fmaf(Ak[i * ND + j], x[j], z);
            maha = fmaf(z, z, maha);
        }
        float logp = fmaf(-0.5f, maha, kconst[k]);
        float t = logp + lw[k];
        float nm = fmaxf(m, t);
        float ea = __expf(m - nm);
        float eb = __expf(t - nm);
        s = s * ea + eb;
        w = fmaf(eb, logp, w * ea);
        m = nm;
    }

    float ll = active ? (w / s) : 0.0f;
#pragma unroll
    for (int off = 32; off > 0; off >>= 1) ll += __shfl_down(ll, off);
    if (threadIdx.x == 0) atomicAdd(acc, ll);
}

__global__ void gmm_final(const float* __restrict__ acc, float* __restrict__ out) {
    out[0] = -acc[0] / (float)NS;
}

extern "C" void kernel_launch(void* const* d_in, const int* in_sizes, int n_in,
                              void* d_out, int out_size, void* d_ws, size_t ws_size,
                              hipStream_t stream) {
    const float* X           = (const float*)d_in[0];
    const float* means       = (const float*)d_in[1];
    const float* scale_tril  = (const float*)d_in[2];
    const float* log_weights = (const float*)d_in[3];

    float* ws     = (float*)d_ws;
    float* A      = ws;
    float* c      = A + NC * ND * ND;
    float* kconst = c + NC * ND;
    float* lw     = kconst + NC;
    float* acc    = lw + NC;

    gmm_setup<<<NC, ND, 0, stream>>>(means, scale_tril, log_weights,
                                     A, c, kconst, lw, acc);
    int blocks = (NS + 63) / 64;
    gmm_main<<<blocks, 64, 0, stream>>>(X, A, c, kconst, lw, acc);
    gmm_final<<<1, 1, 0, stream>>>(acc, (float*)d_out);
}

// Round 2
// 156.491 us; speedup vs baseline: 3.3747x; 3.3747x over previous
//
#include <hip/hip_runtime.h>
#include <math.h>

#define NS 100000
#define NC 64
#define ND 32
#define NT 4            // 16-sample n-tiles per wave -> 64 samples/wave

typedef __attribute__((ext_vector_type(8))) __bf16 bf16x8;
typedef __attribute__((ext_vector_type(4))) float  floatx4;

// ws layout (floats):
//   Bbf    [NC*ND*ND ushorts = 32768 floats]  = bf16(L^{-1}) rows, row-major [2048][32]
//   c      [NC*ND]   = A_k * mu_k (fp32)
//   kconst [NC]      = -0.5*D*log(2pi) - sum(log diag L_k)
//   lw     [NC]      = log_softmax(log_weights)
//   acc    [1]       = sum of per-sample log-likelihoods

__device__ __forceinline__ unsigned short bf16_rne(float f) {
    unsigned int u = __float_as_uint(f);
    u += 0x7FFFu + ((u >> 16) & 1u);
    return (unsigned short)(u >> 16);
}

__global__ void gmm_setup(const float* __restrict__ means,
                          const float* __restrict__ scale_tril,
                          const float* __restrict__ log_weights,
                          unsigned short* __restrict__ Bb,
                          float* __restrict__ c,
                          float* __restrict__ kconst,
                          float* __restrict__ lw,
                          float* __restrict__ acc) {
    int k = blockIdx.x;      // component
    int j = threadIdx.x;     // column of A (0..31)
    __shared__ float Ls[ND * ND];
    __shared__ float Acol[ND][ND + 1];

    // stage L in LDS (the R1 version re-read global L in the inner loop: ~60us)
    for (int idx = j; idx < ND * ND; idx += ND)
        Ls[idx] = scale_tril[(size_t)k * ND * ND + idx];
    __syncthreads();

    // Forward substitution: column j of A = L^{-1}. Each thread owns its column.
    for (int i = 0; i < ND; ++i) {
        float s = (i == j) ? 1.0f : 0.0f;
        for (int l = j; l < i; ++l) s -= Ls[i * ND + l] * Acol[l][j];
        Acol[i][j] = (i >= j) ? (s / Ls[i * ND + i]) : 0.0f;
    }
    __syncthreads();

    // bf16 copy of A rows for MFMA a-operand
    for (int i = 0; i < ND; ++i)
        Bb[(size_t)(k * ND + i) * ND + j] = bf16_rne(Acol[i][j]);

    // c[j] = sum_t A[j][t] * mu[t]
    const float* mu = means + k * ND;
    float cv = 0.0f;
    for (int t = 0; t < ND; ++t) cv += Acol[j][t] * mu[t];
    c[k * ND + j] = cv;

    if (j == 0) {
        float hld = 0.0f;
        for (int i = 0; i < ND; ++i) hld += logf(Ls[i * ND + i]);
        const float LOG2PI = 1.8378770664093453f;
        kconst[k] = -0.5f * (float)ND * LOG2PI - hld;
        float mx = log_weights[0];
        for (int t = 1; t < NC; ++t) mx = fmaxf(mx, log_weights[t]);
        float se = 0.0f;
        for (int t = 0; t < NC; ++t) se += __expf(log_weights[t] - mx);
        lw[k] = log_weights[k] - mx - logf(se);
        if (k == 0) acc[0] = 0.0f;
    }
}

// Per wave: 64 samples x all 64 components via mfma_f32_16x16x32_bf16.
// a-operand: A-row tile (m=lane&15 -> row-in-tile, k=quad*8+j -> feature)
// b-operand: X        (n=lane&15 -> sample,      k=quad*8+j -> feature)
// C/D: col=lane&15 (sample), row=quad*4+reg (row-in-tile)
__launch_bounds__(256)
__global__ void gmm_main(const float* __restrict__ X,
                         const unsigned short* __restrict__ Bb,
                         const float* __restrict__ c,
                         const float* __restrict__ kconst,
                         const float* __restrict__ lw,
                         float* __restrict__ acc) {
    __shared__ float c_s[NC * ND];   // 8 KB
    int tid = threadIdx.x;
    for (int i = tid; i < NC * ND; i += 256) c_s[i] = c[i];
    __syncthreads();

    const int lane = tid & 63;
    const int wave = tid >> 6;
    const int quad = lane >> 4;
    const int col  = lane & 15;
    const int base = (blockIdx.x * 4 + wave) * 64;

    // load X fragments: 8 consecutive features per lane, bf16
    union { unsigned short u[8]; bf16x8 v; } xb[NT];
#pragma unroll
    for (int nt = 0; nt < NT; ++nt) {
        int n = base + nt * 16 + col;
        int nc2 = n < NS ? n : NS - 1;
        const float4* xp = (const float4*)(X + (size_t)nc2 * ND + quad * 8);
        float4 lo = xp[0], hi = xp[1];
        xb[nt].u[0] = bf16_rne(lo.x); xb[nt].u[1] = bf16_rne(lo.y);
        xb[nt].u[2] = bf16_rne(lo.z); xb[nt].u[3] = bf16_rne(lo.w);
        xb[nt].u[4] = bf16_rne(hi.x); xb[nt].u[5] = bf16_rne(hi.y);
        xb[nt].u[6] = bf16_rne(hi.z); xb[nt].u[7] = bf16_rne(hi.w);
    }

    float s[NT], w[NT], t0[NT];
#pragma unroll
    for (int nt = 0; nt < NT; ++nt) { s[nt] = 0.0f; w[nt] = 0.0f; t0[nt] = 0.0f; }

    const int aoff = col * ND + quad * 8;   // element offset within a 16x32 tile row-block

    for (int k = 0; k < NC; ++k) {
        // a-frags: rows [0..15] and [16..31] of component k (1KB each, coalesced)
        bf16x8 a0 = *(const bf16x8*)(Bb + (size_t)k * 1024 + aoff);
        bf16x8 a1 = *(const bf16x8*)(Bb + (size_t)k * 1024 + 512 + aoff);
        floatx4 cLo = *(const floatx4*)(&c_s[k * ND + quad * 4]);
        floatx4 cHi = *(const floatx4*)(&c_s[k * ND + quad * 4 + 16]);

        floatx4 zero = {0.0f, 0.0f, 0.0f, 0.0f};
        floatx4 accA[NT], accB[NT];
#pragma unroll
        for (int nt = 0; nt < NT; ++nt) {
            accA[nt] = __builtin_amdgcn_mfma_f32_16x16x32_bf16(a0, xb[nt].v, zero, 0, 0, 0);
            accB[nt] = __builtin_amdgcn_mfma_f32_16x16x32_bf16(a1, xb[nt].v, zero, 0, 0, 0);
        }

        float kc = kconst[k];
        float lwk = lw[k];
#pragma unroll
        for (int nt = 0; nt < NT; ++nt) {
            float sq = 0.0f;
#pragma unroll
            for (int r = 0; r < 4; ++r) {
                float d0 = accA[nt][r] - cLo[r];  sq = fmaf(d0, d0, sq);
                float d1 = accB[nt][r] - cHi[r];  sq = fmaf(d1, d1, sq);
            }
            // reduce over the 4 quads (rows) -> full maha, replicated
            sq += __shfl_xor(sq, 16);
            sq += __shfl_xor(sq, 32);
            float logp = fmaf(-0.5f, sq, kc);
            float t = logp + lwk;
            if (k == 0) t0[nt] = t;         // uniform branch; anchor cancels in w/s
            float e = __expf(t - t0[nt]);
            s[nt] += e;
            w[nt] = fmaf(e, logp, w[nt]);
        }
    }

    float ll = 0.0f;
#pragma unroll
    for (int nt = 0; nt < NT; ++nt) {
        int n = base + nt * 16 + col;
        float v = w[nt] / s[nt];
        ll += (n < NS) ? v : 0.0f;
    }
    // values are replicated across the 4 quads -> full butterfly gives 4x the sum
#pragma unroll
    for (int off = 1; off < 64; off <<= 1) ll += __shfl_xor(ll, off);
    if (lane == 0) atomicAdd(acc, ll * 0.25f);
}

__global__ void gmm_final(const float* __restrict__ acc, float* __restrict__ out) {
    out[0] = -acc[0] / (float)NS;
}

extern "C" void kernel_launch(void* const* d_in, const int* in_sizes, int n_in,
                              void* d_out, int out_size, void* d_ws, size_t ws_size,
                              hipStream_t stream) {
    const float* X           = (const float*)d_in[0];
    const float* means       = (const float*)d_in[1];
    const float* scale_tril  = (const float*)d_in[2];
    const float* log_weights = (const float*)d_in[3];

    float* ws       = (float*)d_ws;
    unsigned short* Bb = (unsigned short*)ws;            // 32768 floats worth
    float* c        = ws + (NC * ND * ND) / 2;
    float* kconst   = c + NC * ND;
    float* lw       = kconst + NC;
    float* acc      = lw + NC;

    gmm_setup<<<NC, ND, 0, stream>>>(means, scale_tril, log_weights,
                                     Bb, c, kconst, lw, acc);
    int blocks = (NS + 255) / 256;   // 4 waves/block, 64 samples/wave
    gmm_main<<<blocks, 256, 0, stream>>>(X, Bb, c, kconst, lw, acc);
    gmm_final<<<1, 1, 0, stream>>>(acc, (float*)d_out);
}

// Round 3
// 146.027 us; speedup vs baseline: 3.6165x; 1.0717x over previous
//
#include <hip/hip_runtime.h>
#include <math.h>

#define NS 100000
#define NC 64
#define ND 32
#define NK 576          // 18 k-tiles of 32 features
#define LOG2PI 1.8378770664093453f

typedef __attribute__((ext_vector_type(8))) __bf16 bf16x8;
typedef __attribute__((ext_vector_type(8))) float  floatx8;
typedef __attribute__((ext_vector_type(4))) float  floatx4;

// ws layout (bytes):
//   Qw      [NC*NK __bf16]  = 73728 B : per-comp logp coefficient rows
//   lw      [NC floats]               : log_softmax(log_weights)
//   acc     [1 float]
//   counter [1 uint]

// Feature ordering (kf = t*32 + u, u = quad*8+jj at the lane level):
//   t in [0,16):  f = x_u * x_{(u+t)&31}        (t=0: squares; else circulant pairs)
//   t == 16:      u<16: f = x_u * x_{u+16}  ; u>=16: f = x_{u-16}   (linear lo)
//   t == 17:      u<16: f = x_{16+u}        ; u==16: f = 1 ; else 0 (linear hi + const)
// Every unordered pair {i,j} appears exactly once; coefs below match.

__global__ void gmm_setup(const float* __restrict__ means,
                          const float* __restrict__ scale_tril,
                          const float* __restrict__ log_weights,
                          __bf16* __restrict__ Qw,
                          float* __restrict__ lw,
                          float* __restrict__ acc,
                          unsigned int* __restrict__ counter) {
    int k = blockIdx.x;
    int tid = threadIdx.x;           // 64 threads
    __shared__ float Ls[ND * ND];
    __shared__ float Ac[ND][ND + 1]; // Ac[j][i] = A[i][j] (column j of A=L^-1)
    __shared__ float P[ND][ND + 1];  // P = A^T A (full symmetric)
    __shared__ float bb[ND];         // b = P mu
    __shared__ float mu_s[ND];

    for (int idx = tid; idx < ND * ND; idx += 64)
        Ls[idx] = scale_tril[(size_t)k * ND * ND + idx];
    if (tid < ND) mu_s[tid] = means[k * ND + tid];
    __syncthreads();

    if (tid < ND) {
        int j = tid;
        float a[ND];
        // forward substitution, fully unrolled; a[i]=0 for i<j falls out naturally
#pragma unroll
        for (int i = 0; i < ND; ++i) {
            float s = (i == j) ? 1.0f : 0.0f;
#pragma unroll
            for (int l = 0; l < ND; ++l)
                if (l < i) s -= Ls[i * ND + l] * a[l];
            a[i] = s / Ls[i * ND + i];
            if (i < j) a[i] = 0.0f;
        }
#pragma unroll
        for (int i = 0; i < ND; ++i) Ac[j][i] = a[i];
    }
    __syncthreads();

    // P[i][j] = sum_l Ac[i][l]*Ac[j][l]; thread t: i=t&31, j in [16*(t>>5), +16)
    {
        int i = tid & 31, h = tid >> 5;
        for (int j = 16 * h; j < 16 * h + 16; ++j) {
            float s = 0.0f;
#pragma unroll
            for (int l = 0; l < ND; ++l) s += Ac[i][l] * Ac[j][l];
            P[i][j] = s;
        }
    }
    __syncthreads();
    if (tid < ND) {
        float s = 0.0f;
        for (int j = 0; j < ND; ++j) s += P[tid][j] * mu_s[j];
        bb[tid] = s;
    }
    __syncthreads();

    // emit Q row for component k
    for (int kf = tid; kf < NK; kf += 64) {
        int t = kf >> 5, u = kf & 31;
        float val;
        if (t == 0) val = -0.5f * P[u][u];
        else if (t < 16) val = -P[u][(u + t) & 31];
        else if (t == 16) val = (u < 16) ? -P[u][u + 16] : bb[u - 16];
        else { // t == 17
            if (u < 16) val = bb[16 + u];
            else if (u == 16) {
                float cc = 0.0f;
                for (int i = 0; i < ND; ++i) cc += mu_s[i] * bb[i];
                float hld = 0.0f;
                for (int i = 0; i < ND; ++i) hld += logf(Ls[i * ND + i]);
                float kconst = -0.5f * (float)ND * LOG2PI - hld;
                val = -0.5f * cc + kconst;
            } else val = 0.0f;
        }
        Qw[(size_t)k * NK + kf] = (__bf16)val;
    }

    if (k == 0) {
        // log_softmax of log_weights; every thread handles one component
        float mx = log_weights[0];
        for (int t = 1; t < NC; ++t) mx = fmaxf(mx, log_weights[t]);
        float se = 0.0f;
        for (int t = 0; t < NC; ++t) se += __expf(log_weights[t] - mx);
        lw[tid] = log_weights[tid] - mx - logf(se);
        if (tid == 0) { acc[0] = 0.0f; counter[0] = 0u; }
    }
}

__launch_bounds__(256, 2)
__global__ void gmm_main(const float* __restrict__ X,
                         const __bf16* __restrict__ Qw,
                         const float* __restrict__ lw,
                         float* __restrict__ acc,
                         unsigned int* __restrict__ counter,
                         float* __restrict__ out) {
    __shared__ float lw_s[NC];
    int tid = threadIdx.x;
    if (tid < NC) lw_s[tid] = lw[tid];
    __syncthreads();

    const int lane = tid & 63;
    const int wave = tid >> 6;
    const int quad = lane >> 4;
    const int col  = lane & 15;
    const int base = (blockIdx.x * 4 + wave) * 64;

    floatx4 lwr[4];
#pragma unroll
    for (int mt = 0; mt < 4; ++mt)
        lwr[mt] = *(const floatx4*)&lw_s[mt * 16 + quad * 4];

    float ll = 0.0f;

#pragma unroll
    for (int pair = 0; pair < 2; ++pair) {
        int n0 = base + pair * 32 + col;
        int n1 = n0 + 16;
        int n0c = n0 < NS ? n0 : NS - 1;
        int n1c = n1 < NS ? n1 : NS - 1;

        // rotated x: xr[m] = x[(m + 8*quad) & 31]  (compile-time reg indices later)
        float xr0[ND], xr1[ND];
        {
            const float4* p0 = (const float4*)(X + (size_t)n0c * ND);
            const float4* p1 = (const float4*)(X + (size_t)n1c * ND);
#pragma unroll
            for (int g = 0; g < 8; ++g) {
                float4 v = p0[(g + 2 * quad) & 7];
                xr0[4*g+0]=v.x; xr0[4*g+1]=v.y; xr0[4*g+2]=v.z; xr0[4*g+3]=v.w;
                float4 u = p1[(g + 2 * quad) & 7];
                xr1[4*g+0]=u.x; xr1[4*g+1]=u.y; xr1[4*g+2]=u.z; xr1[4*g+3]=u.w;
            }
        }

        floatx4 A0[4], A1[4];
#pragma unroll
        for (int mt = 0; mt < 4; ++mt) {
            A0[mt] = (floatx4){0.f,0.f,0.f,0.f};
            A1[mt] = (floatx4){0.f,0.f,0.f,0.f};
        }

#pragma unroll
        for (int t = 0; t < 18; ++t) {
            floatx8 f0, f1;
#pragma unroll
            for (int jj = 0; jj < 8; ++jj) {
                if (t < 16) {
                    f0[jj] = xr0[jj] * xr0[(jj + t) & 31];
                    f1[jj] = xr1[jj] * xr1[(jj + t) & 31];
                } else if (t == 16) {
                    float a0 = (quad < 2) ? xr0[jj] : 1.0f;
                    float a1 = (quad < 2) ? xr1[jj] : 1.0f;
                    f0[jj] = a0 * xr0[(jj + 16) & 31];
                    f1[jj] = a1 * xr1[(jj + 16) & 31];
                } else { // t == 17
                    float c = (quad == 2 && jj == 0) ? 1.0f : 0.0f;
                    f0[jj] = (quad < 2) ? xr0[(jj + 16) & 31] : c;
                    f1[jj] = (quad < 2) ? xr1[(jj + 16) & 31] : c;
                }
            }
            bf16x8 b0 = __builtin_convertvector(f0, bf16x8);
            bf16x8 b1 = __builtin_convertvector(f1, bf16x8);
#pragma unroll
            for (int mt = 0; mt < 4; ++mt) {
                bf16x8 af = *(const bf16x8*)(Qw + (size_t)(mt * 16 + col) * NK + t * 32 + quad * 8);
                A0[mt] = __builtin_amdgcn_mfma_f32_16x16x32_bf16(af, b0, A0[mt], 0, 0, 0);
                A1[mt] = __builtin_amdgcn_mfma_f32_16x16x32_bf16(af, b1, A1[mt], 0, 0, 0);
            }
        }

        // epilogue: lane holds logp for 16 comps (mt*16 + quad*4 + r) of its sample
        float s0 = 0.f, w0 = 0.f, s1 = 0.f, w1 = 0.f;
#pragma unroll
        for (int mt = 0; mt < 4; ++mt) {
#pragma unroll
            for (int r = 0; r < 4; ++r) {
                float lp0 = A0[mt][r];
                float e0 = __expf(lp0 + lwr[mt][r]);
                s0 += e0; w0 = fmaf(e0, lp0, w0);
                float lp1 = A1[mt][r];
                float e1 = __expf(lp1 + lwr[mt][r]);
                s1 += e1; w1 = fmaf(e1, lp1, w1);
            }
        }
        s0 += __shfl_xor(s0, 16); s0 += __shfl_xor(s0, 32);
        w0 += __shfl_xor(w0, 16); w0 += __shfl_xor(w0, 32);
        s1 += __shfl_xor(s1, 16); s1 += __shfl_xor(s1, 32);
        w1 += __shfl_xor(w1, 16); w1 += __shfl_xor(w1, 32);
        ll += (n0 < NS) ? (w0 / s0) : 0.0f;
        ll += (n1 < NS) ? (w1 / s1) : 0.0f;
    }

    // values replicated across 4 quads -> butterfly gives 4x the per-wave sum
#pragma unroll
    for (int off = 1; off < 64; off <<= 1) ll += __shfl_xor(ll, off);
    if (lane == 0) {
        atomicAdd(acc, ll * 0.25f);
        __threadfence();
        unsigned int tk = atomicAdd(counter, 1u);
        if (tk == gridDim.x * 4 - 1) {
            float tot = atomicAdd(acc, 0.0f);   // coherent read of final sum
            out[0] = -tot / (float)NS;
        }
    }
}

extern "C" void kernel_launch(void* const* d_in, const int* in_sizes, int n_in,
                              void* d_out, int out_size, void* d_ws, size_t ws_size,
                              hipStream_t stream) {
    const float* X           = (const float*)d_in[0];
    const float* means       = (const float*)d_in[1];
    const float* scale_tril  = (const float*)d_in[2];
    const float* log_weights = (const float*)d_in[3];

    char* ws = (char*)d_ws;
    __bf16*       Qw      = (__bf16*)ws;                       // 73728 B
    float*        lw      = (float*)(ws + NC * NK * 2);        // 256 B
    float*        acc     = (float*)(ws + NC * NK * 2 + 256);
    unsigned int* counter = (unsigned int*)(ws + NC * NK * 2 + 260);

    gmm_setup<<<NC, 64, 0, stream>>>(means, scale_tril, log_weights,
                                     Qw, lw, acc, counter);
    int blocks = (NS + 255) / 256;   // 4 waves/block, 64 samples/wave
    gmm_main<<<blocks, 256, 0, stream>>>(X, Qw, lw, acc, counter, (float*)d_out);
}

// Round 4
// 133.794 us; speedup vs baseline: 3.9471x; 1.0914x over previous
//
#include <hip/hip_runtime.h>
#include <math.h>

#define NS 100000
#define NC 64
#define ND 32
#define NK 576          // 18 k-tiles of 32 features
#define LOG2PI 1.8378770664093453f

typedef __attribute__((ext_vector_type(8))) __bf16 bf16x8;
typedef __attribute__((ext_vector_type(8))) float  floatx8;
typedef __attribute__((ext_vector_type(4))) float  floatx4;

// ws layout (bytes):
//   Qf      [NC*NK __bf16 = 73728 B] : Q in MFMA a-fragment order:
//             chunk index (mt*18 + t)*64 + lane, 8 bf16 per chunk (16 B).
//             lane = quad*16 + colk encodes (comp = mt*16+colk, feat = t*32+quad*8+jj)
//   lw      [NC floats] : log_softmax(log_weights)
//   kc      [NC floats] : kconst_k - 0.5*mu^T P mu  (fp32 — too big for bf16)
//   acc     [1 float]
//   counter [1 uint]

// Feature map (u = quad*8+jj within tile t):
//   t in [0,16):  f = x_u * x_{(u+t)&31}   coef: t==0 ? -0.5*P_uu : -P[u][(u+t)&31]
//   t == 16:      u<16: f = x_u*x_{u+16} (coef -P)  ; u>=16: f = x_{u-16} (coef b)
//   t == 17:      u<16: f = x_{16+u} (coef b)       ; u>=16: f = const slot, coef 0
// Every unordered pair {i,j} appears exactly once (496 pairs + 32 sq + 32 lin).

__global__ void gmm_setup(const float* __restrict__ means,
                          const float* __restrict__ scale_tril,
                          const float* __restrict__ log_weights,
                          __bf16* __restrict__ Qf,
                          float* __restrict__ lw,
                          float* __restrict__ kc,
                          float* __restrict__ acc,
                          unsigned int* __restrict__ counter) {
    int k = blockIdx.x;
    int tid = threadIdx.x;           // 64 threads
    __shared__ float Ls[ND * ND];
    __shared__ float Ac[ND][ND + 1]; // Ac[j][i] = A[i][j] (column j of A=L^-1)
    __shared__ float P[ND][ND + 1];  // P = A^T A (full symmetric)
    __shared__ float bb[ND];         // b = P mu
    __shared__ float mu_s[ND];

    for (int idx = tid; idx < ND * ND; idx += 64)
        Ls[idx] = scale_tril[(size_t)k * ND * ND + idx];
    if (tid < ND) mu_s[tid] = means[k * ND + tid];
    __syncthreads();

    if (tid < ND) {
        int j = tid;
        float a[ND];
#pragma unroll
        for (int i = 0; i < ND; ++i) {
            float s = (i == j) ? 1.0f : 0.0f;
#pragma unroll
            for (int l = 0; l < ND; ++l)
                if (l < i) s -= Ls[i * ND + l] * a[l];
            a[i] = s / Ls[i * ND + i];
            if (i < j) a[i] = 0.0f;
        }
#pragma unroll
        for (int i = 0; i < ND; ++i) Ac[j][i] = a[i];
    }
    __syncthreads();

    // P[i][j] = sum_l Ac[i][l]*Ac[j][l]
    {
        int i = tid & 31, h = tid >> 5;
        for (int j = 16 * h; j < 16 * h + 16; ++j) {
            float s = 0.0f;
#pragma unroll
            for (int l = 0; l < ND; ++l) s += Ac[i][l] * Ac[j][l];
            P[i][j] = s;
        }
    }
    __syncthreads();
    if (tid < ND) {
        float s = 0.0f;
        for (int j = 0; j < ND; ++j) s += P[tid][j] * mu_s[j];
        bb[tid] = s;
    }
    __syncthreads();

    // emit Q row for component k in fragment order
    int mt = k >> 4, colk = k & 15;
    for (int kf = tid; kf < NK; kf += 64) {
        int t = kf >> 5, u = kf & 31;
        int quad = u >> 3, jj = u & 7;
        float val;
        if (t == 0) val = -0.5f * P[u][u];
        else if (t < 16) val = -P[u][(u + t) & 31];
        else if (t == 16) val = (u < 16) ? -P[u][u + 16] : bb[u - 16];
        else val = (u < 16) ? bb[16 + u] : 0.0f;   // const moved to fp32 kc
        Qf[(size_t)(((mt * 18 + t) * 64 + quad * 16 + colk) * 8 + jj)] = (__bf16)val;
    }

    if (tid == 0) {
        float cc = 0.0f, hld = 0.0f;
        for (int i = 0; i < ND; ++i) { cc += mu_s[i] * bb[i]; hld += logf(Ls[i * ND + i]); }
        kc[k] = -0.5f * cc + (-0.5f * (float)ND * LOG2PI - hld);
    }
    if (k == 0) {
        float mx = log_weights[0];
        for (int t = 1; t < NC; ++t) mx = fmaxf(mx, log_weights[t]);
        float se = 0.0f;
        for (int t = 0; t < NC; ++t) se += __expf(log_weights[t] - mx);
        lw[tid] = log_weights[tid] - mx - logf(se);
        if (tid == 0) { acc[0] = 0.0f; counter[0] = 0u; }
    }
}

__launch_bounds__(256, 2)
__global__ void gmm_main(const float* __restrict__ X,
                         const __bf16* __restrict__ Qf,
                         const float* __restrict__ lw,
                         const float* __restrict__ kc,
                         float* __restrict__ acc,
                         unsigned int* __restrict__ counter,
                         float* __restrict__ out) {
    __shared__ float lw_s[NC];
    __shared__ float kc_s[NC];
    int tid = threadIdx.x;
    if (tid < NC) { lw_s[tid] = lw[tid]; kc_s[tid] = kc[tid]; }
    __syncthreads();

    const int lane = tid & 63;
    const int wave = tid >> 6;
    const int quad = lane >> 4;
    const int base = (blockIdx.x * 4 + wave) * 64;

    float ll = 0.0f;

#pragma unroll
    for (int pair = 0; pair < 2; ++pair) {
        int n0 = base + pair * 32 + (lane & 15);
        int n1 = n0 + 16;
        int n0c = n0 < NS ? n0 : NS - 1;
        int n1c = n1 < NS ? n1 : NS - 1;

        // rotated x: xr[m] = x[(m + 8*quad) & 31]
        float xr0[ND], xr1[ND];
        {
            const float4* p0 = (const float4*)(X + (size_t)n0c * ND);
            const float4* p1 = (const float4*)(X + (size_t)n1c * ND);
#pragma unroll
            for (int g = 0; g < 8; ++g) {
                float4 v = p0[(g + 2 * quad) & 7];
                xr0[4*g+0]=v.x; xr0[4*g+1]=v.y; xr0[4*g+2]=v.z; xr0[4*g+3]=v.w;
                float4 u = p1[(g + 2 * quad) & 7];
                xr1[4*g+0]=u.x; xr1[4*g+1]=u.y; xr1[4*g+2]=u.z; xr1[4*g+3]=u.w;
            }
        }

        floatx4 A0[4], A1[4];
#pragma unroll
        for (int mt = 0; mt < 4; ++mt) {
            A0[mt] = (floatx4){0.f,0.f,0.f,0.f};
            A1[mt] = (floatx4){0.f,0.f,0.f,0.f};
        }

#pragma unroll
        for (int t = 0; t < 18; ++t) {
            floatx8 f0, f1;
#pragma unroll
            for (int jj = 0; jj < 8; ++jj) {
                if (t < 16) {
                    f0[jj] = xr0[jj] * xr0[(jj + t) & 31];
                    f1[jj] = xr1[jj] * xr1[(jj + t) & 31];
                } else if (t == 16) {
                    float a0 = (quad < 2) ? xr0[jj] : 1.0f;
                    float a1 = (quad < 2) ? xr1[jj] : 1.0f;
                    f0[jj] = a0 * xr0[(jj + 16) & 31];
                    f1[jj] = a1 * xr1[(jj + 16) & 31];
                } else { // t == 17: linear hi for quad<2; zero-coef slots otherwise
                    f0[jj] = (quad < 2) ? xr0[(jj + 16) & 31] : 0.0f;
                    f1[jj] = (quad < 2) ? xr1[(jj + 16) & 31] : 0.0f;
                }
            }
            bf16x8 b0 = __builtin_convertvector(f0, bf16x8);
            bf16x8 b1 = __builtin_convertvector(f1, bf16x8);
#pragma unroll
            for (int mt = 0; mt < 4; ++mt) {
                // fragment-ordered: wave reads base + lane*16B, fully coalesced
                bf16x8 af = *(const bf16x8*)(Qf + (size_t)(((mt * 18 + t) * 64 + lane) * 8));
                A0[mt] = __builtin_amdgcn_mfma_f32_16x16x32_bf16(af, b0, A0[mt], 0, 0, 0);
                A1[mt] = __builtin_amdgcn_mfma_f32_16x16x32_bf16(af, b1, A1[mt], 0, 0, 0);
            }
        }

        // epilogue: lane holds logp for comps (mt*16 + quad*4 + r) of its sample
        float s0 = 0.f, w0 = 0.f, s1 = 0.f, w1 = 0.f;
#pragma unroll
        for (int mt = 0; mt < 4; ++mt) {
            floatx4 lwv = *(const floatx4*)&lw_s[mt * 16 + quad * 4];  // broadcast
            floatx4 kcv = *(const floatx4*)&kc_s[mt * 16 + quad * 4];
#pragma unroll
            for (int r = 0; r < 4; ++r) {
                float lp0 = A0[mt][r] + kcv[r];
                float e0 = __expf(lp0 + lwv[r]);
                s0 += e0; w0 = fmaf(e0, lp0, w0);
                float lp1 = A1[mt][r] + kcv[r];
                float e1 = __expf(lp1 + lwv[r]);
                s1 += e1; w1 = fmaf(e1, lp1, w1);
            }
        }
        s0 += __shfl_xor(s0, 16); s0 += __shfl_xor(s0, 32);
        w0 += __shfl_xor(w0, 16); w0 += __shfl_xor(w0, 32);
        s1 += __shfl_xor(s1, 16); s1 += __shfl_xor(s1, 32);
        w1 += __shfl_xor(w1, 16); w1 += __shfl_xor(w1, 32);
        ll += (n0 < NS) ? (w0 / s0) : 0.0f;
        ll += (n1 < NS) ? (w1 / s1) : 0.0f;
    }

    // values replicated across 4 quads -> butterfly gives 4x the per-wave sum
#pragma unroll
    for (int off = 1; off < 64; off <<= 1) ll += __shfl_xor(ll, off);
    if (lane == 0) {
        atomicAdd(acc, ll * 0.25f);
        __threadfence();
        unsigned int tk = atomicAdd(counter, 1u);
        if (tk == gridDim.x * 4 - 1) {
            float tot = atomicAdd(acc, 0.0f);   // coherent read of final sum
            out[0] = -tot / (float)NS;
        }
    }
}

extern "C" void kernel_launch(void* const* d_in, const int* in_sizes, int n_in,
                              void* d_out, int out_size, void* d_ws, size_t ws_size,
                              hipStream_t stream) {
    const float* X           = (const float*)d_in[0];
    const float* means       = (const float*)d_in[1];
    const float* scale_tril  = (const float*)d_in[2];
    const float* log_weights = (const float*)d_in[3];

    char* ws = (char*)d_ws;
    __bf16*       Qf      = (__bf16*)ws;                        // 73728 B
    float*        lw      = (float*)(ws + NC * NK * 2);         // 256 B
    float*        kc      = lw + NC;                            // 256 B
    float*        acc     = kc + NC;
    unsigned int* counter = (unsigned int*)(acc + 1);

    gmm_setup<<<NC, 64, 0, stream>>>(means, scale_tril, log_weights,
                                     Qf, lw, kc, acc, counter);
    int blocks = (NS + 255) / 256;   // 4 waves/block, 64 samples/wave
    gmm_main<<<blocks, 256, 0, stream>>>(X, Qf, lw, kc, acc, counter, (float*)d_out);
}

// Round 5
// 111.049 us; speedup vs baseline: 4.7556x; 1.2048x over previous
//
#include <hip/hip_runtime.h>
#include <math.h>

#define NS 100000
#define NC 64
#define ND 32
#define NK 576          // 18 k-tiles of 32 features
#define LOG2PI 1.8378770664093453f

typedef __attribute__((ext_vector_type(8))) __bf16 bf16x8;
typedef __attribute__((ext_vector_type(8))) float  floatx8;
typedef __attribute__((ext_vector_type(4))) float  floatx4;

// ws layout (bytes):
//   Qf      [NC*NK __bf16 = 73728 B] : Q in MFMA a-fragment order:
//             chunk index (mt*18 + t)*64 + lane, 8 bf16 per chunk (16 B).
//   lw      [NC floats] @ 73728 : log_softmax(log_weights)
//   kc      [NC floats] @ 73984 : kconst_k - 0.5*mu^T P mu  (fp32)
//   acc     [float]     @ 74240 : global sum       (own cache line)
//   counter [uint]      @ 74496 : completion ticket (own cache line)

// Feature map (u = quad*8+jj within tile t):
//   t in [0,16):  f = x_u * x_{(u+t)&31}   coef: t==0 ? -0.5*P_uu : -P[u][(u+t)&31]
//   t == 16:      u<16: f = x_u*x_{u+16} (coef -P)  ; u>=16: f = x_{u-16} (coef b)
//   t == 17:      u<16: f = x_{16+u} (coef b)       ; u>=16: zero-coef slots

__global__ void gmm_setup(const float* __restrict__ means,
                          const float* __restrict__ scale_tril,
                          const float* __restrict__ log_weights,
                          __bf16* __restrict__ Qf,
                          float* __restrict__ lw,
                          float* __restrict__ kc,
                          float* __restrict__ acc,
                          unsigned int* __restrict__ counter) {
    int k = blockIdx.x;
    int tid = threadIdx.x;           // 64 threads
    __shared__ float Ls[ND * ND];
    __shared__ float Ac[ND][ND + 1]; // Ac[j][i] = A[i][j] (column j of A=L^-1)
    __shared__ float P[ND][ND + 1];  // P = A^T A (full symmetric)
    __shared__ float bb[ND];         // b = P mu
    __shared__ float mu_s[ND];

    for (int idx = tid; idx < ND * ND; idx += 64)
        Ls[idx] = scale_tril[(size_t)k * ND * ND + idx];
    if (tid < ND) mu_s[tid] = means[k * ND + tid];
    __syncthreads();

    if (tid < ND) {
        int j = tid;
        float a[ND];
#pragma unroll
        for (int i = 0; i < ND; ++i) {
            float s = (i == j) ? 1.0f : 0.0f;
#pragma unroll
            for (int l = 0; l < ND; ++l)
                if (l < i) s -= Ls[i * ND + l] * a[l];
            a[i] = s / Ls[i * ND + i];
            if (i < j) a[i] = 0.0f;
        }
#pragma unroll
        for (int i = 0; i < ND; ++i) Ac[j][i] = a[i];
    }
    __syncthreads();

    // P[i][j] = sum_l Ac[i][l]*Ac[j][l]
    {
        int i = tid & 31, h = tid >> 5;
        for (int j = 16 * h; j < 16 * h + 16; ++j) {
            float s = 0.0f;
#pragma unroll
            for (int l = 0; l < ND; ++l) s += Ac[i][l] * Ac[j][l];
            P[i][j] = s;
        }
    }
    __syncthreads();
    if (tid < ND) {
        float s = 0.0f;
        for (int j = 0; j < ND; ++j) s += P[tid][j] * mu_s[j];
        bb[tid] = s;
    }
    __syncthreads();

    // emit Q row for component k in fragment order
    int mt = k >> 4, colk = k & 15;
    for (int kf = tid; kf < NK; kf += 64) {
        int t = kf >> 5, u = kf & 31;
        int quad = u >> 3, jj = u & 7;
        float val;
        if (t == 0) val = -0.5f * P[u][u];
        else if (t < 16) val = -P[u][(u + t) & 31];
        else if (t == 16) val = (u < 16) ? -P[u][u + 16] : bb[u - 16];
        else val = (u < 16) ? bb[16 + u] : 0.0f;   // const lives in fp32 kc
        Qf[(size_t)(((mt * 18 + t) * 64 + quad * 16 + colk) * 8 + jj)] = (__bf16)val;
    }

    if (tid == 0) {
        float cc = 0.0f, hld = 0.0f;
        for (int i = 0; i < ND; ++i) { cc += mu_s[i] * bb[i]; hld += logf(Ls[i * ND + i]); }
        kc[k] = -0.5f * cc + (-0.5f * (float)ND * LOG2PI - hld);
    }
    if (k == 0) {
        float mx = log_weights[0];
        for (int t = 1; t < NC; ++t) mx = fmaxf(mx, log_weights[t]);
        float se = 0.0f;
        for (int t = 0; t < NC; ++t) se += __expf(log_weights[t] - mx);
        lw[tid] = log_weights[tid] - mx - logf(se);
        if (tid == 0) { acc[0] = 0.0f; counter[0] = 0u; }
    }
}

// One n-pair (32 samples) per wave, 128 samples/block, 782 blocks.
__launch_bounds__(256, 3)
__global__ void gmm_main(const float* __restrict__ X,
                         const __bf16* __restrict__ Qf,
                         const float* __restrict__ lw,
                         const float* __restrict__ kc,
                         float* __restrict__ acc,
                         unsigned int* __restrict__ counter,
                         float* __restrict__ out) {
    __shared__ float lw_s[NC];
    __shared__ float kc_s[NC];
    __shared__ float partial[4];
    int tid = threadIdx.x;
    if (tid < NC) { lw_s[tid] = lw[tid]; kc_s[tid] = kc[tid]; }
    __syncthreads();

    const int lane = tid & 63;
    const int wave = tid >> 6;
    const int quad = lane >> 4;

    int n0 = blockIdx.x * 128 + wave * 32 + (lane & 15);
    int n1 = n0 + 16;
    int n0c = n0 < NS ? n0 : NS - 1;
    int n1c = n1 < NS ? n1 : NS - 1;

    // rotated x: xr[m] = x[(m + 8*quad) & 31]
    float xr0[ND], xr1[ND];
    {
        const float4* p0 = (const float4*)(X + (size_t)n0c * ND);
        const float4* p1 = (const float4*)(X + (size_t)n1c * ND);
#pragma unroll
        for (int g = 0; g < 8; ++g) {
            float4 v = p0[(g + 2 * quad) & 7];
            xr0[4*g+0]=v.x; xr0[4*g+1]=v.y; xr0[4*g+2]=v.z; xr0[4*g+3]=v.w;
            float4 u = p1[(g + 2 * quad) & 7];
            xr1[4*g+0]=u.x; xr1[4*g+1]=u.y; xr1[4*g+2]=u.z; xr1[4*g+3]=u.w;
        }
    }

    floatx4 A0[4], A1[4];
#pragma unroll
    for (int mt = 0; mt < 4; ++mt) {
        A0[mt] = (floatx4){0.f,0.f,0.f,0.f};
        A1[mt] = (floatx4){0.f,0.f,0.f,0.f};
    }

#pragma unroll
    for (int t = 0; t < 18; ++t) {
        floatx8 f0, f1;
#pragma unroll
        for (int jj = 0; jj < 8; ++jj) {
            if (t < 16) {
                f0[jj] = xr0[jj] * xr0[(jj + t) & 31];
                f1[jj] = xr1[jj] * xr1[(jj + t) & 31];
            } else if (t == 16) {
                float a0 = (quad < 2) ? xr0[jj] : 1.0f;
                float a1 = (quad < 2) ? xr1[jj] : 1.0f;
                f0[jj] = a0 * xr0[(jj + 16) & 31];
                f1[jj] = a1 * xr1[(jj + 16) & 31];
            } else {
                f0[jj] = (quad < 2) ? xr0[(jj + 16) & 31] : 0.0f;
                f1[jj] = (quad < 2) ? xr1[(jj + 16) & 31] : 0.0f;
            }
        }
        bf16x8 b0 = __builtin_convertvector(f0, bf16x8);
        bf16x8 b1 = __builtin_convertvector(f1, bf16x8);
#pragma unroll
        for (int mt = 0; mt < 4; ++mt) {
            bf16x8 af = *(const bf16x8*)(Qf + (size_t)(((mt * 18 + t) * 64 + lane) * 8));
            A0[mt] = __builtin_amdgcn_mfma_f32_16x16x32_bf16(af, b0, A0[mt], 0, 0, 0);
            A1[mt] = __builtin_amdgcn_mfma_f32_16x16x32_bf16(af, b1, A1[mt], 0, 0, 0);
        }
    }

    // epilogue: lane holds logp for comps (mt*16 + quad*4 + r) of its sample
    float s0 = 0.f, w0 = 0.f, s1 = 0.f, w1 = 0.f;
#pragma unroll
    for (int mt = 0; mt < 4; ++mt) {
        floatx4 lwv = *(const floatx4*)&lw_s[mt * 16 + quad * 4];
        floatx4 kcv = *(const floatx4*)&kc_s[mt * 16 + quad * 4];
#pragma unroll
        for (int r = 0; r < 4; ++r) {
            float lp0 = A0[mt][r] + kcv[r];
            float e0 = __expf(lp0 + lwv[r]);
            s0 += e0; w0 = fmaf(e0, lp0, w0);
            float lp1 = A1[mt][r] + kcv[r];
            float e1 = __expf(lp1 + lwv[r]);
            s1 += e1; w1 = fmaf(e1, lp1, w1);
        }
    }
    s0 += __shfl_xor(s0, 16); s0 += __shfl_xor(s0, 32);
    w0 += __shfl_xor(w0, 16); w0 += __shfl_xor(w0, 32);
    s1 += __shfl_xor(s1, 16); s1 += __shfl_xor(s1, 32);
    w1 += __shfl_xor(w1, 16); w1 += __shfl_xor(w1, 32);

    float ll = 0.0f;
    ll += (n0 < NS) ? (w0 / s0) : 0.0f;
    ll += (n1 < NS) ? (w1 / s1) : 0.0f;

    // replicated across 4 quads -> butterfly gives 4x the per-wave sum
#pragma unroll
    for (int off = 1; off < 64; off <<= 1) ll += __shfl_xor(ll, off);
    if (lane == 0) partial[wave] = ll * 0.25f;
    __syncthreads();

    // ONE atomic per block (was: per wave + shared cache line with counter)
    if (tid == 0) {
        float tot = partial[0] + partial[1] + partial[2] + partial[3];
        atomicAdd(acc, tot);
        __threadfence();
        unsigned int tk = atomicAdd(counter, 1u);
        if (tk == gridDim.x - 1) {
            float t2 = atomicAdd(acc, 0.0f);   // coherent read of final sum
            out[0] = -t2 / (float)NS;
        }
    }
}

extern "C" void kernel_launch(void* const* d_in, const int* in_sizes, int n_in,
                              void* d_out, int out_size, void* d_ws, size_t ws_size,
                              hipStream_t stream) {
    const float* X           = (const float*)d_in[0];
    const float* means       = (const float*)d_in[1];
    const float* scale_tril  = (const float*)d_in[2];
    const float* log_weights = (const float*)d_in[3];

    char* ws = (char*)d_ws;
    __bf16*       Qf      = (__bf16*)ws;                  // 73728 B
    float*        lw      = (float*)(ws + 73728);
    float*        kc      = (float*)(ws + 73984);
    float*        acc     = (float*)(ws + 74240);         // own cache line
    unsigned int* counter = (unsigned int*)(ws + 74496);  // own cache line

    gmm_setup<<<NC, 64, 0, stream>>>(means, scale_tril, log_weights,
                                     Qf, lw, kc, acc, counter);
    int blocks = (NS + 127) / 128;   // 782: 4 waves/block, 32 samples/wave
    gmm_main<<<blocks, 256, 0, stream>>>(X, Qf, lw, kc, acc, counter, (float*)d_out);
}

// Round 6
// 100.256 us; speedup vs baseline: 5.2675x; 1.1077x over previous
//
#include <hip/hip_runtime.h>
#include <math.h>

#define NS 100000
#define NC 64
#define ND 32
#define NK 576          // 18 k-tiles of 32 features
#define NBLK ((NS + 127) / 128)   // 782 main blocks
#define LOG2PI 1.8378770664093453f

typedef __attribute__((ext_vector_type(8))) __bf16 bf16x8;
typedef __attribute__((ext_vector_type(8))) float  floatx8;
typedef __attribute__((ext_vector_type(4))) float  floatx4;

// ws layout (bytes):
//   Qf  [NC*NK __bf16 = 73728 B] : Q in MFMA a-fragment order:
//         chunk index (mt*18 + t)*64 + lane, 8 bf16 per chunk (16 B).
//   lw  [NC floats] @ 73728 : log_softmax(log_weights)
//   kc  [NC floats] @ 73984 : kconst_k - 0.5*mu^T P mu  (fp32)
//   pb  [NBLK floats] @ 74240 : per-block partials (no atomics anywhere)

// Feature map (u = quad*8+jj within tile t):
//   t in [0,16):  f = x_u * x_{(u+t)&31}   coef: t==0 ? -0.5*P_uu : -P[u][(u+t)&31]
//   t == 16:      u<16: f = x_u*x_{u+16} (coef -P)  ; u>=16: f = x_{u-16} (coef b)
//   t == 17:      u<16: f = x_{16+u} (coef b)       ; u>=16: zero-coef slots

__global__ void gmm_setup(const float* __restrict__ means,
                          const float* __restrict__ scale_tril,
                          const float* __restrict__ log_weights,
                          __bf16* __restrict__ Qf,
                          float* __restrict__ lw,
                          float* __restrict__ kc) {
    int k = blockIdx.x;
    int tid = threadIdx.x;           // 64 threads
    __shared__ float Ls[ND * ND];
    __shared__ float Ac[ND][ND + 1]; // Ac[j][i] = A[i][j] (column j of A=L^-1)
    __shared__ float P[ND][ND + 1];  // P = A^T A (full symmetric)
    __shared__ float bb[ND];         // b = P mu
    __shared__ float mu_s[ND];

    for (int idx = tid; idx < ND * ND; idx += 64)
        Ls[idx] = scale_tril[(size_t)k * ND * ND + idx];
    if (tid < ND) mu_s[tid] = means[k * ND + tid];
    __syncthreads();

    if (tid < ND) {
        int j = tid;
        float a[ND];
#pragma unroll
        for (int i = 0; i < ND; ++i) {
            float s = (i == j) ? 1.0f : 0.0f;
#pragma unroll
            for (int l = 0; l < ND; ++l)
                if (l < i) s -= Ls[i * ND + l] * a[l];
            a[i] = s / Ls[i * ND + i];
            if (i < j) a[i] = 0.0f;
        }
#pragma unroll
        for (int i = 0; i < ND; ++i) Ac[j][i] = a[i];
    }
    __syncthreads();

    // P[i][j] = sum_l Ac[i][l]*Ac[j][l]
    {
        int i = tid & 31, h = tid >> 5;
        for (int j = 16 * h; j < 16 * h + 16; ++j) {
            float s = 0.0f;
#pragma unroll
            for (int l = 0; l < ND; ++l) s += Ac[i][l] * Ac[j][l];
            P[i][j] = s;
        }
    }
    __syncthreads();
    if (tid < ND) {
        float s = 0.0f;
        for (int j = 0; j < ND; ++j) s += P[tid][j] * mu_s[j];
        bb[tid] = s;
    }
    __syncthreads();

    // emit Q row for component k in fragment order
    int mt = k >> 4, colk = k & 15;
    for (int kf = tid; kf < NK; kf += 64) {
        int t = kf >> 5, u = kf & 31;
        int quad = u >> 3, jj = u & 7;
        float val;
        if (t == 0) val = -0.5f * P[u][u];
        else if (t < 16) val = -P[u][(u + t) & 31];
        else if (t == 16) val = (u < 16) ? -P[u][u + 16] : bb[u - 16];
        else val = (u < 16) ? bb[16 + u] : 0.0f;   // const lives in fp32 kc
        Qf[(size_t)(((mt * 18 + t) * 64 + quad * 16 + colk) * 8 + jj)] = (__bf16)val;
    }

    if (tid == 0) {
        float cc = 0.0f, hld = 0.0f;
        for (int i = 0; i < ND; ++i) { cc += mu_s[i] * bb[i]; hld += logf(Ls[i * ND + i]); }
        kc[k] = -0.5f * cc + (-0.5f * (float)ND * LOG2PI - hld);
    }
    if (k == 0) {
        float mx = log_weights[0];
        for (int t = 1; t < NC; ++t) mx = fmaxf(mx, log_weights[t]);
        float se = 0.0f;
        for (int t = 0; t < NC; ++t) se += __expf(log_weights[t] - mx);
        lw[tid] = log_weights[tid] - mx - logf(se);
    }
}

// One n-pair (32 samples) per wave, 128 samples/block, 782 blocks.
// NO global atomics: each block writes its partial to pb[blockIdx.x].
__launch_bounds__(256, 3)
__global__ void gmm_main(const float* __restrict__ X,
                         const __bf16* __restrict__ Qf,
                         const float* __restrict__ lw,
                         const float* __restrict__ kc,
                         float* __restrict__ pb) {
    __shared__ float lw_s[NC];
    __shared__ float kc_s[NC];
    __shared__ float partial[4];
    int tid = threadIdx.x;
    if (tid < NC) { lw_s[tid] = lw[tid]; kc_s[tid] = kc[tid]; }
    __syncthreads();

    const int lane = tid & 63;
    const int wave = tid >> 6;
    const int quad = lane >> 4;

    int n0 = blockIdx.x * 128 + wave * 32 + (lane & 15);
    int n1 = n0 + 16;
    int n0c = n0 < NS ? n0 : NS - 1;
    int n1c = n1 < NS ? n1 : NS - 1;

    // rotated x: xr[m] = x[(m + 8*quad) & 31]
    float xr0[ND], xr1[ND];
    {
        const float4* p0 = (const float4*)(X + (size_t)n0c * ND);
        const float4* p1 = (const float4*)(X + (size_t)n1c * ND);
#pragma unroll
        for (int g = 0; g < 8; ++g) {
            float4 v = p0[(g + 2 * quad) & 7];
            xr0[4*g+0]=v.x; xr0[4*g+1]=v.y; xr0[4*g+2]=v.z; xr0[4*g+3]=v.w;
            float4 u = p1[(g + 2 * quad) & 7];
            xr1[4*g+0]=u.x; xr1[4*g+1]=u.y; xr1[4*g+2]=u.z; xr1[4*g+3]=u.w;
        }
    }

    floatx4 A0[4], A1[4];
#pragma unroll
    for (int mt = 0; mt < 4; ++mt) {
        A0[mt] = (floatx4){0.f,0.f,0.f,0.f};
        A1[mt] = (floatx4){0.f,0.f,0.f,0.f};
    }

#pragma unroll
    for (int t = 0; t < 18; ++t) {
        floatx8 f0, f1;
#pragma unroll
        for (int jj = 0; jj < 8; ++jj) {
            if (t < 16) {
                f0[jj] = xr0[jj] * xr0[(jj + t) & 31];
                f1[jj] = xr1[jj] * xr1[(jj + t) & 31];
            } else if (t == 16) {
                float a0 = (quad < 2) ? xr0[jj] : 1.0f;
                float a1 = (quad < 2) ? xr1[jj] : 1.0f;
                f0[jj] = a0 * xr0[(jj + 16) & 31];
                f1[jj] = a1 * xr1[(jj + 16) & 31];
            } else {
                f0[jj] = (quad < 2) ? xr0[(jj + 16) & 31] : 0.0f;
                f1[jj] = (quad < 2) ? xr1[(jj + 16) & 31] : 0.0f;
            }
        }
        bf16x8 b0 = __builtin_convertvector(f0, bf16x8);
        bf16x8 b1 = __builtin_convertvector(f1, bf16x8);
#pragma unroll
        for (int mt = 0; mt < 4; ++mt) {
            bf16x8 af = *(const bf16x8*)(Qf + (size_t)(((mt * 18 + t) * 64 + lane) * 8));
            A0[mt] = __builtin_amdgcn_mfma_f32_16x16x32_bf16(af, b0, A0[mt], 0, 0, 0);
            A1[mt] = __builtin_amdgcn_mfma_f32_16x16x32_bf16(af, b1, A1[mt], 0, 0, 0);
        }
    }

    // epilogue: lane holds logp for comps (mt*16 + quad*4 + r) of its sample
    float s0 = 0.f, w0 = 0.f, s1 = 0.f, w1 = 0.f;
#pragma unroll
    for (int mt = 0; mt < 4; ++mt) {
        floatx4 lwv = *(const floatx4*)&lw_s[mt * 16 + quad * 4];
        floatx4 kcv = *(const floatx4*)&kc_s[mt * 16 + quad * 4];
#pragma unroll
        for (int r = 0; r < 4; ++r) {
            float lp0 = A0[mt][r] + kcv[r];
            float e0 = __expf(lp0 + lwv[r]);
            s0 += e0; w0 = fmaf(e0, lp0, w0);
            float lp1 = A1[mt][r] + kcv[r];
            float e1 = __expf(lp1 + lwv[r]);
            s1 += e1; w1 = fmaf(e1, lp1, w1);
        }
    }
    s0 += __shfl_xor(s0, 16); s0 += __shfl_xor(s0, 32);
    w0 += __shfl_xor(w0, 16); w0 += __shfl_xor(w0, 32);
    s1 += __shfl_xor(s1, 16); s1 += __shfl_xor(s1, 32);
    w1 += __shfl_xor(w1, 16); w1 += __shfl_xor(w1, 32);

    float ll = 0.0f;
    ll += (n0 < NS) ? (w0 / s0) : 0.0f;
    ll += (n1 < NS) ? (w1 / s1) : 0.0f;

    // replicated across 4 quads -> butterfly gives 4x the per-wave sum
#pragma unroll
    for (int off = 1; off < 64; off <<= 1) ll += __shfl_xor(ll, off);
    if (lane == 0) partial[wave] = ll * 0.25f;
    __syncthreads();

    if (tid == 0)
        pb[blockIdx.x] = partial[0] + partial[1] + partial[2] + partial[3];
}

__global__ void gmm_reduce(const float* __restrict__ pb, float* __restrict__ out) {
    int tid = threadIdx.x;   // 256 threads
    float s = 0.0f;
    for (int i = tid; i < NBLK; i += 256) s += pb[i];
#pragma unroll
    for (int off = 32; off > 0; off >>= 1) s += __shfl_down(s, off);
    __shared__ float wsum[4];
    if ((tid & 63) == 0) wsum[tid >> 6] = s;
    __syncthreads();
    if (tid == 0)
        out[0] = -(wsum[0] + wsum[1] + wsum[2] + wsum[3]) / (float)NS;
}

extern "C" void kernel_launch(void* const* d_in, const int* in_sizes, int n_in,
                              void* d_out, int out_size, void* d_ws, size_t ws_size,
                              hipStream_t stream) {
    const float* X           = (const float*)d_in[0];
    const float* means       = (const float*)d_in[1];
    const float* scale_tril  = (const float*)d_in[2];
    const float* log_weights = (const float*)d_in[3];

    char* ws = (char*)d_ws;
    __bf16* Qf = (__bf16*)ws;                  // 73728 B
    float*  lw = (float*)(ws + 73728);
    float*  kc = (float*)(ws + 73984);
    float*  pb = (float*)(ws + 74240);         // NBLK floats

    gmm_setup<<<NC, 64, 0, stream>>>(means, scale_tril, log_weights, Qf, lw, kc);
    gmm_main<<<NBLK, 256, 0, stream>>>(X, Qf, lw, kc, pb);
    gmm_reduce<<<1, 256, 0, stream>>>(pb, (float*)d_out);
}